// Round 14
// baseline (116.758 us; speedup 1.0000x reference)
//
#include <hip/hip_runtime.h>
#include <hip/hip_bf16.h>

#define LSEQ   200
#define LPAD   208
#define EMB    32
#define TDIM   128
#define COND   160
#define ROWS   321
#define MASK_T 48
#define LL_LDB 80      // LL row stride bytes (64B data + 16B pad)

typedef __attribute__((ext_vector_type(8))) short          short8;
typedef __attribute__((ext_vector_type(4))) float          f32x4;

__device__ __forceinline__ float bf2f(unsigned short u) {
    union { unsigned int i; float f; } v; v.i = ((unsigned int)u) << 16; return v.f;
}
__device__ __forceinline__ float asf(unsigned int u) {
    union { unsigned int i; float f; } v; v.i = u; return v.f;
}
__device__ __forceinline__ unsigned int f2bf(float f) {
    union { float f; unsigned int i; } v; v.f = f;
    unsigned int x = v.i;
    return ((x + 0x7fffu + ((x >> 16) & 1u)) >> 16);   // RNE, low 16
}
__device__ __forceinline__ unsigned int pack2(float lo, float hi) {
    return f2bf(lo) | (f2bf(hi) << 16);
}

template<int CTRL>
__device__ __forceinline__ float dpp_add(float v) {
    const int x = __builtin_amdgcn_update_dpp(0, __float_as_int(v), CTRL, 0xf, 0xf, true);
    return v + __int_as_float(x);
}
__device__ __forceinline__ float red16(float v) {
    v = dpp_add<0x128>(v);   // row_ror:8
    v = dpp_add<0x124>(v);   // row_ror:4
    v = dpp_add<0x122>(v);   // row_ror:2
    v = dpp_add<0x121>(v);   // row_ror:1
    return v;
}

// ---- prep (49 blocks): te_tab[49][128] bf16; T1t[160][52] f32; te_t[128][52] bf16;
//      T2w4[49][16][16] bf16: tile T -> wave wg (0:T<3,1:T<6,2:T<8,3:else), slot = T-{0,3,6,8};
//      T2w4[t][lc][wg*4+slot] = T2[t][T*16+lc]; row t==48 -> 0.
//      Block 0 additionally emits w2b[160][32] bf16 (w2 cols 0..31, frag-ready).
__global__ void prep(const float* __restrict__ w1, const float* __restrict__ w2,
                     unsigned short* __restrict__ te_tab, float* __restrict__ T1t,
                     unsigned short* __restrict__ te_t, unsigned short* __restrict__ T2w4,
                     unsigned short* __restrict__ w2b) {
    __shared__ float te128[TDIM];
    const int t = blockIdx.x, tid = threadIdx.x;
    if (tid < 64) {
        const float dv = __expf(-0.14391156f * (float)tid);  // 10000^(-tid/64)
        const float a  = (float)t * dv;
        const float s  = __sinf(a), c = __cosf(a);
        te128[2 * tid] = s; te128[2 * tid + 1] = c;
        ((unsigned int*)te_tab)[t * 64 + tid] = pack2(s, c);
    }
    __syncthreads();
    if (tid < COND) {
        float s1 = 0.0f, s2 = 0.0f;
        const float* w1r = w1 + tid * COND + EMB;
        const float* w2r = w2 + tid * COND + EMB;
        #pragma unroll 8
        for (int j = 0; j < TDIM; ++j) {
            s1 = fmaf(te128[j], w1r[j], s1);
            s2 = fmaf(te128[j], w2r[j], s2);
        }
        if (t == MASK_T) { s1 = 0.0f; s2 = 0.0f; }
        T1t[tid * 52 + t] = s1;
        const int tile = tid >> 4, lcc = tid & 15;
        const int wg   = (tile < 3) ? 0 : (tile < 6) ? 1 : (tile < 8) ? 2 : 3;
        const int slot = tile - ((wg == 0) ? 0 : (wg == 1) ? 3 : (wg == 2) ? 6 : 8);
        T2w4[t * 256 + lcc * 16 + wg * 4 + slot] = (unsigned short)f2bf(s2);
    }
    if (tid < TDIM) te_t[tid * 52 + t] = (unsigned short)f2bf(te128[tid]);
    if (t == 0 && tid < COND) {       // w2b row tid: cols 0..31 -> bf16
        const float* src = w2 + (size_t)tid * COND;
        unsigned int* dst = (unsigned int*)(w2b + tid * 32);
        #pragma unroll
        for (int j = 0; j < 16; ++j)
            dst[j] = pack2(src[2 * j], src[2 * j + 1]);
    }
}

// ---- main: one batch per 256-thread block (4 waves), n-split GEMM (bf[<=3]/wave) ----
__global__ __launch_bounds__(256) __attribute__((amdgpu_waves_per_eu(4, 8)))
void fused4(const int*   __restrict__ tp,
            const int*   __restrict__ loc,
            const float* __restrict__ emb,
            const int*   __restrict__ st,        // [B][L][2]
            const float* __restrict__ loc_emb,   // [V][32] fp32
            const float* __restrict__ noise,
            const int*   __restrict__ tstep,
            const float* __restrict__ w1,        // fp32 (cols 0..31 used)
            const unsigned short* __restrict__ w2b,    // [160][32] bf16
            const unsigned short* __restrict__ te_tab,
            const float* __restrict__ T1t,       // [160][52]
            const unsigned short* __restrict__ te_t,   // [128][52]
            const unsigned short* __restrict__ T2w4,   // [49][16][16]
            const float* __restrict__ b2,
            const float* __restrict__ wc,
            const float* __restrict__ alpha_hat,
            float* __restrict__ out)             // [B][321][32]
{
    __shared__ __attribute__((aligned(16))) unsigned char LL[LPAD * LL_LDB]; // 16,640
    __shared__ float scoreW[LSEQ];                       // 800
    __shared__ float su[320];                            // 1,280 [side|uemb]
    __shared__ float m1W[COND];                          // 640
    __shared__ __attribute__((aligned(16))) float mupart[4][EMB];   // 512
    __shared__ __attribute__((aligned(16))) float cntsb[52];        // 208
    __shared__ __attribute__((aligned(4)))  unsigned char ttr[LPAD];// 208

    const int tid  = threadIdx.x;
    const int w    = tid >> 6, lane = tid & 63;
    const int b    = blockIdx.x;
    const int lc   = lane & 15, lg = lane >> 4;
    const int rsub = lane >> 3, csub = lane & 7;
    const int2* st2 = (const int2*)st;
    float* outb = out + (size_t)b * (ROWS * EMB);

    // ---- P0: side row, noisy row, zero-init ----
    if (w == 0) {
        if (lane < 32) {
            const ushort4 tv = *(const ushort4*)(te_tab + tp[b] * TDIM + lane * 4);
            f32x4 s4 = { bf2f(tv.x), bf2f(tv.y), bf2f(tv.z), bf2f(tv.w) };
            *(f32x4*)(su + lane * 4) = s4;
        } else if (lane < 40) {
            *(f32x4*)(su + 128 + (lane - 32) * 4) =
                *(const f32x4*)(loc_emb + (size_t)(loc[b] - 1) * EMB + (lane - 32) * 4);
        } else if (lane < 48) {
            const int e4 = lane - 40;
            const float a  = alpha_hat[tstep[b]];
            const float sa = sqrtf(a), sn = sqrtf(1.0f - a);
            const f32x4 ev = *(const f32x4*)(emb + (size_t)b * EMB + e4 * 4);
            const f32x4 nv = *(const f32x4*)(noise + (size_t)b * EMB + e4 * 4);
            f32x4 r = { sa*ev[0]+sn*nv[0], sa*ev[1]+sn*nv[1],
                        sa*ev[2]+sn*nv[2], sa*ev[3]+sn*nv[3] };
            *(f32x4*)(outb + 320 * EMB + e4 * 4) = r;
        }
    } else if (w == 1) {
        if (lane < 52) cntsb[lane] = 0.0f;
        if (lane < 50) {                              // zero scoreW (atomic target)
            f32x4 z = {0.f, 0.f, 0.f, 0.f};
            *(f32x4*)(scoreW + lane * 4) = z;
        }
        if (lane >= 52 && lane < 60) {                // zero-pad rows 200..207
            const int r = 200 + lane - 52;
            uint4 z = make_uint4(0, 0, 0, 0);
            *(uint4*)(LL + r * LL_LDB)      = z;
            *(uint4*)(LL + r * LL_LDB + 16) = z;
            *(uint4*)(LL + r * LL_LDB + 32) = z;
            *(uint4*)(LL + r * LL_LDB + 48) = z;
            ttr[r] = 0;
        }
    }
    __syncthreads();   // B0

    // ---- P1a: ttr + cnt histogram (wave w owns rows w*50..w*50+49) ----
    int tA = MASK_T;
    if (lane < 50) {
        const int r = w * 50 + lane;
        const int2 sv = st2[(size_t)b * LSEQ + r];
        ttr[r] = (unsigned char)sv.y;
        tA = sv.y;
        if (sv.y != MASK_T) atomicAdd(&cntsb[sv.y], 1.0f);
    }

    // ---- P1b: quarter-row gather -> LL(bf16) + mean partials ----
    f32x4 macc = {0.f, 0.f, 0.f, 0.f};
    #pragma unroll
    for (int i = 0; i < 7; ++i) {
        const int rr = i * 8 + rsub;
        if (rr < 50) {
            const int row = w * 50 + rr;
            const int s0 = st2[(size_t)b * LSEQ + row].x - 1;
            const f32x4 v = *(const f32x4*)(loc_emb + (size_t)s0 * EMB + csub * 4);
            macc += v;
            uint2 pv = make_uint2(pack2(v[0], v[1]), pack2(v[2], v[3]));
            *(uint2*)(LL + row * LL_LDB + csub * 8) = pv;
        }
    }
    #pragma unroll
    for (int sh = 8; sh < 64; sh <<= 1) {
        macc[0] += __shfl_xor(macc[0], sh);
        macc[1] += __shfl_xor(macc[1], sh);
        macc[2] += __shfl_xor(macc[2], sh);
        macc[3] += __shfl_xor(macc[3], sh);
    }
    if (rsub == 0) *(f32x4*)(&mupart[w][csub * 4]) = macc;
    __syncthreads();   // B1

    // ---- P2: m1[c] = b2 + (colsum@w1[:, :32]^T + cnt@T1t)/200 ----
    if (tid < COND) {
        const int c = tid;
        f32x4 mm[8];
        #pragma unroll
        for (int j = 0; j < 8; ++j)
            mm[j] = ((const f32x4*)mupart[0])[j] + ((const f32x4*)mupart[1])[j]
                  + ((const f32x4*)mupart[2])[j] + ((const f32x4*)mupart[3])[j];
        f32x4 d = {0.f, 0.f, 0.f, 0.f};
        const f32x4* w1r = (const f32x4*)(w1 + (size_t)c * COND);
        #pragma unroll
        for (int j = 0; j < 8; ++j) d += mm[j] * w1r[j];
        const f32x4* t1r = (const f32x4*)(T1t + c * 52);
        #pragma unroll
        for (int q = 0; q < 13; ++q)
            d += ((const f32x4*)cntsb)[q] * t1r[q];
        m1W[c] = b2[c] + (d[0] + d[1] + d[2] + d[3]) * 0.005f;
    }
    __syncthreads();   // B2

    if (w == 1 && lane < 52) cntsb[lane] = 0.0f;   // re-zero as sb (read after B3)

    // ---- P3: this wave's 2-3 B-frags (late load -> short live range) ----
    const int  t0  = (w < 2) ? 3 * w : 6 + 2 * (w - 2);   // 0,3,6,8
    const bool tn3 = (w < 2);
    short8 bf0, bf1, bf2v = short8{0,0,0,0,0,0,0,0};
    float m10, m11, m12 = 0.0f, wc0, wc1, wc2 = 0.0f;
    {
        const int c0 = t0 * 16 + lc, c1 = (t0 + 1) * 16 + lc;
        bf0 = *(const short8*)(w2b + c0 * 32 + lg * 8);
        bf1 = *(const short8*)(w2b + c1 * 32 + lg * 8);
        m10 = m1W[c0]; wc0 = wc[c0];
        m11 = m1W[c1]; wc1 = wc[c1];
        if (tn3) {
            const int c2 = (t0 + 2) * 16 + lc;
            bf2v = *(const short8*)(w2b + c2 * 32 + lg * 8);
            m12 = m1W[c2]; wc2 = wc[c2];
        }
    }

    // ---- P4: all 13 m-tiles x this wave's n-tiles; partial score via LDS atomics ----
    for (int m = 0; m < 13; ++m) {
        const short8 av = *(const short8*)(LL + (m * 16 + lc) * LL_LDB + lg * 16);
        const uchar4 tq = *(const uchar4*)(ttr + m * 16 + lg * 4);
        f32x4 z = {0.f, 0.f, 0.f, 0.f};
        f32x4 a0 = __builtin_amdgcn_mfma_f32_16x16x32_bf16(av, bf0, z, 0, 0, 0);
        f32x4 a1 = __builtin_amdgcn_mfma_f32_16x16x32_bf16(av, bf1, z, 0, 0, 0);
        f32x4 a2 = z;
        if (tn3) a2 = __builtin_amdgcn_mfma_f32_16x16x32_bf16(av, bf2v, z, 0, 0, 0);

        f32x4 srow;
        #pragma unroll
        for (int r = 0; r < 4; ++r) {
            const int t = (r == 0) ? tq.x : (r == 1) ? tq.y : (r == 2) ? tq.z : tq.w;
            const ushort4 q = *(const ushort4*)(T2w4 + t * 256 + lc * 16 + w * 4);
            float s = wc0 * __builtin_amdgcn_rcpf(1.0f + __expf(-(a0[r] + m10 + bf2f(q.x))))
                    + wc1 * __builtin_amdgcn_rcpf(1.0f + __expf(-(a1[r] + m11 + bf2f(q.y))));
            if (tn3)
                s += wc2 * __builtin_amdgcn_rcpf(1.0f + __expf(-(a2[r] + m12 + bf2f(q.z))));
            srow[r] = red16(s);
        }
        if (lc == 0) {
            #pragma unroll
            for (int r = 0; r < 4; ++r) {
                const int row = m * 16 + lg * 4 + r;
                if (row < LSEQ) atomicAdd(&scoreW[row], srow[r]);
            }
        }
    }
    __syncthreads();   // B3

    // ---- P5a: sb histogram ----
    if (lane < 50) {
        const float sc = scoreW[w * 50 + lane];
        if (tA != MASK_T) atomicAdd(&cntsb[tA], sc);
    }
    // ---- P5: uemb_loc quarter-row partials from LL ----
    f32x4 uacc = {0.f, 0.f, 0.f, 0.f};
    #pragma unroll
    for (int i = 0; i < 7; ++i) {
        const int rr = i * 8 + rsub;
        if (rr < 50) {
            const int row = w * 50 + rr;
            const float sc = scoreW[row];
            const uint2 pv = *(const uint2*)(LL + row * LL_LDB + csub * 8);
            uacc[0] = fmaf(sc, asf(pv.x << 16), uacc[0]);
            uacc[1] = fmaf(sc, asf(pv.x & 0xffff0000u), uacc[1]);
            uacc[2] = fmaf(sc, asf(pv.y << 16), uacc[2]);
            uacc[3] = fmaf(sc, asf(pv.y & 0xffff0000u), uacc[3]);
        }
    }
    #pragma unroll
    for (int sh = 8; sh < 64; sh <<= 1) {
        uacc[0] += __shfl_xor(uacc[0], sh);
        uacc[1] += __shfl_xor(uacc[1], sh);
        uacc[2] += __shfl_xor(uacc[2], sh);
        uacc[3] += __shfl_xor(uacc[3], sh);
    }
    if (rsub == 0) *(f32x4*)(&mupart[w][csub * 4]) = uacc;
    __syncthreads();   // B4

    // ---- P5b: uemb_te (tid<128) + uemb_loc combine (tid 128..159) ----
    if (tid < TDIM) {
        const int j = tid;
        const unsigned short* ter = te_t + j * 52;
        float s = 0.0f;
        #pragma unroll
        for (int q = 0; q < 13; ++q) {
            const f32x4 sq = ((const f32x4*)cntsb)[q];
            const ushort4 tv = *(const ushort4*)(ter + q * 4);
            s = fmaf(sq[0], bf2f(tv.x), s);
            s = fmaf(sq[1], bf2f(tv.y), s);
            s = fmaf(sq[2], bf2f(tv.z), s);
            s = fmaf(sq[3], bf2f(tv.w), s);
        }
        su[192 + j] = s;
    } else if (tid < TDIM + 32) {
        const int col = tid - TDIM;
        su[160 + col] = mupart[0][col] + mupart[1][col]
                      + mupart[2][col] + mupart[3][col];
    }
    __syncthreads();   // B5

    // ---- P6: broadcast-write rows 0..319 ----
    #pragma unroll
    for (int k = 0; k < 10; ++k) {
        const int idx = tid + k * 256;
        const int row = idx >> 3;
        const float v = su[row];
        f32x4 vv = {v, v, v, v};
        *(f32x4*)(outb + row * EMB + (idx & 7) * 4) = vv;
    }
}

extern "C" void kernel_launch(void* const* d_in, const int* in_sizes, int n_in,
                              void* d_out, int out_size, void* d_ws, size_t ws_size,
                              hipStream_t stream) {
    const int*   tp        = (const int*)  d_in[0];
    const int*   loc       = (const int*)  d_in[1];
    const float* emb       = (const float*)d_in[2];
    const int*   st        = (const int*)  d_in[3];
    const float* loc_emb   = (const float*)d_in[4];
    const float* noise     = (const float*)d_in[5];
    const int*   tstep     = (const int*)  d_in[6];
    const float* w1        = (const float*)d_in[7];
    const float* w2        = (const float*)d_in[8];
    const float* b2        = (const float*)d_in[9];
    const float* wc        = (const float*)d_in[10];
    const float* alpha_hat = (const float*)d_in[11];
    float* out = (float*)d_out;

    char* ws = (char*)d_ws;
    float*          T1t    = (float*)ws;                          // 33,280 B
    unsigned short* te_tab = (unsigned short*)(ws + 33280);       // 12,544 B
    unsigned short* te_t   = (unsigned short*)(ws + 45824);       // 13,312 B
    unsigned short* T2w4   = (unsigned short*)(ws + 59136);       // 25,088 B
    unsigned short* w2b    = (unsigned short*)(ws + 84224);       // 10,240 B

    prep<<<49, 256, 0, stream>>>(w1, w2, te_tab, T1t, te_t, T2w4, w2b);

    const int nb = in_sizes[0];   // 2048
    fused4<<<nb, 256, 0, stream>>>(tp, loc, emb, st, loc_emb, noise, tstep,
                                   w1, w2b, te_tab, T1t, te_t, T2w4,
                                   b2, wc, alpha_hat, out);
}

// Round 15
// 85.779 us; speedup vs baseline: 1.3612x; 1.3612x over previous
//
#include <hip/hip_runtime.h>
#include <hip/hip_bf16.h>

#define LSEQ   200
#define LPAD   208
#define EMB    32
#define TDIM   128
#define COND   160
#define ROWS   321
#define MASK_T 48

typedef __attribute__((ext_vector_type(8))) short  short8;
typedef __attribute__((ext_vector_type(4))) float  f32x4;

#define WAIT_LGKM() asm volatile("s_waitcnt lgkmcnt(0)" ::: "memory")

__device__ __forceinline__ float bf2f(unsigned short u) {
    union { unsigned int i; float f; } v; v.i = ((unsigned int)u) << 16; return v.f;
}
__device__ __forceinline__ unsigned int f2bf(float f) {
    union { float f; unsigned int i; } v; v.f = f;
    unsigned int x = v.i;
    return ((x + 0x7fffu + ((x >> 16) & 1u)) >> 16);   // RNE, low 16
}
__device__ __forceinline__ unsigned int pack2(float lo, float hi) {
    return f2bf(lo) | (f2bf(hi) << 16);
}
__device__ __forceinline__ short8 pack8(f32x4 a, f32x4 b) {
    union { short8 s; unsigned int u[4]; } r;
    r.u[0] = pack2(a[0], a[1]); r.u[1] = pack2(a[2], a[3]);
    r.u[2] = pack2(b[0], b[1]); r.u[3] = pack2(b[2], b[3]);
    return r.s;
}

template<int CTRL>
__device__ __forceinline__ float dpp_add(float v) {
    const int x = __builtin_amdgcn_update_dpp(0, __float_as_int(v), CTRL, 0xf, 0xf, true);
    return v + __int_as_float(x);
}
__device__ __forceinline__ float red16(float v) {
    v = dpp_add<0x128>(v);   // row_ror:8
    v = dpp_add<0x124>(v);   // row_ror:4
    v = dpp_add<0x122>(v);   // row_ror:2
    v = dpp_add<0x121>(v);   // row_ror:1
    return v;
}

// ---- prep (49 blocks): te_tab[49][128] bf16; T1t[160][52] f32; te_t[128][52] bf16;
//      T2w2[49][2][16][8] bf16: tile T(0..9) -> pass g=T/5, slot=T%5:
//      T2w2[t][g][lc][slot] = T2[t][T*16+lc]; row t==48 -> 0.
//      Block 0 additionally emits w2b[160][32] bf16 (w2 cols 0..31, frag-ready).
__global__ void prep(const float* __restrict__ w1, const float* __restrict__ w2,
                     unsigned short* __restrict__ te_tab, float* __restrict__ T1t,
                     unsigned short* __restrict__ te_t, unsigned short* __restrict__ T2w2,
                     unsigned short* __restrict__ w2b) {
    __shared__ float te128[TDIM];
    const int t = blockIdx.x, tid = threadIdx.x;
    if (tid < 64) {
        const float dv = __expf(-0.14391156f * (float)tid);  // 10000^(-tid/64)
        const float a  = (float)t * dv;
        const float s  = __sinf(a), c = __cosf(a);
        te128[2 * tid] = s; te128[2 * tid + 1] = c;
        ((unsigned int*)te_tab)[t * 64 + tid] = pack2(s, c);
    }
    __syncthreads();
    if (tid < COND) {
        float s1 = 0.0f, s2 = 0.0f;
        const float* w1r = w1 + tid * COND + EMB;
        const float* w2r = w2 + tid * COND + EMB;
        #pragma unroll 8
        for (int j = 0; j < TDIM; ++j) {
            s1 = fmaf(te128[j], w1r[j], s1);
            s2 = fmaf(te128[j], w2r[j], s2);
        }
        if (t == MASK_T) { s1 = 0.0f; s2 = 0.0f; }
        T1t[tid * 52 + t] = s1;
        const int tile = tid >> 4, lcc = tid & 15;
        const int g = (tile >= 5) ? 1 : 0, slot = tile - 5 * g;
        T2w2[t * 256 + g * 128 + lcc * 8 + slot] = (unsigned short)f2bf(s2);
    }
    if (tid < TDIM) te_t[tid * 52 + t] = (unsigned short)f2bf(te128[tid]);
    if (t == 0 && tid < COND) {       // w2b row tid: cols 0..31 -> bf16
        const float* src = w2 + (size_t)tid * COND;
        unsigned int* dst = (unsigned int*)(w2b + tid * 32);
        #pragma unroll
        for (int j = 0; j < 16; ++j)
            dst[j] = pack2(src[2 * j], src[2 * j + 1]);
    }
}

// ---- main: ONE WAVE PER BATCH, one 64-thread block per batch, zero barriers ----
__global__ __launch_bounds__(64) __attribute__((amdgpu_waves_per_eu(4, 8)))
void fusedw(const int*   __restrict__ tp,
            const int*   __restrict__ loc,
            const float* __restrict__ emb,
            const int*   __restrict__ st,        // [B][L][2]
            const float* __restrict__ loc_emb,   // [V][32] fp32
            const float* __restrict__ noise,
            const int*   __restrict__ tstep,
            const float* __restrict__ w1,        // fp32 (cols 0..31 used)
            const unsigned short* __restrict__ w2b,    // [160][32] bf16
            const unsigned short* __restrict__ te_tab,
            const float* __restrict__ T1t,       // [160][52]
            const unsigned short* __restrict__ te_t,   // [128][52]
            const unsigned short* __restrict__ T2w2,   // [49][2][16][8]
            const float* __restrict__ b2,
            const float* __restrict__ wc,
            const float* __restrict__ alpha_hat,
            float* __restrict__ out)             // [B][321][32]
{
    __shared__ int   ssr[LPAD];                              // 832
    __shared__ float scoreW[LSEQ];                           // 800
    __shared__ float su[320];                                // 1,280 [side|uemb]
    __shared__ float m1W[COND];                              // 640
    __shared__ __attribute__((aligned(16))) float mloc[EMB]; // 128
    __shared__ __attribute__((aligned(16))) float cntW[52];  // 208
    __shared__ __attribute__((aligned(16))) float sbW[52];   // 208
    __shared__ __attribute__((aligned(4))) unsigned char ttr[LPAD]; // 208
    // total ~4.3 KB -> LDS never the residency limit

    const int lane = threadIdx.x;
    const int b    = blockIdx.x;
    const int lc   = lane & 15, lg = lane >> 4;
    const int rsub = lane >> 3, csub = lane & 7;
    const int2* st2 = (const int2*)st;
    float* outb = out + (size_t)b * (ROWS * EMB);

    // ---- P0: zero bins; side row; noisy row ----
    if (lane < 52) { cntW[lane] = 0.0f; sbW[lane] = 0.0f; }
    if (lane < 32) {
        const ushort4 tv = *(const ushort4*)(te_tab + tp[b] * TDIM + lane * 4);
        f32x4 s4 = { bf2f(tv.x), bf2f(tv.y), bf2f(tv.z), bf2f(tv.w) };
        *(f32x4*)(su + lane * 4) = s4;
    } else if (lane < 40) {
        *(f32x4*)(su + 128 + (lane - 32) * 4) =
            *(const f32x4*)(loc_emb + (size_t)(loc[b] - 1) * EMB + (lane - 32) * 4);
    } else if (lane < 48) {
        const int e4 = lane - 40;
        const float a  = alpha_hat[tstep[b]];
        const float sa = sqrtf(a), sn = sqrtf(1.0f - a);
        const f32x4 ev = *(const f32x4*)(emb + (size_t)b * EMB + e4 * 4);
        const f32x4 nv = *(const f32x4*)(noise + (size_t)b * EMB + e4 * 4);
        f32x4 r = { sa*ev[0]+sn*nv[0], sa*ev[1]+sn*nv[1],
                    sa*ev[2]+sn*nv[2], sa*ev[3]+sn*nv[3] };
        *(f32x4*)(outb + 320 * EMB + e4 * 4) = r;
    }

    // ---- P1: ttr/ssr + cnt histogram (rows lane + k*64) ----
    #pragma unroll
    for (int k = 0; k < 4; ++k) {
        const int r = lane + k * 64;
        if (r < LSEQ) {
            const int2 sv = st2[(size_t)b * LSEQ + r];
            ttr[r] = (unsigned char)sv.y;
            ssr[r] = sv.x;
            if (sv.y != MASK_T) atomicAdd(&cntW[sv.y], 1.0f);
        } else if (r < LPAD) {
            ttr[r] = 0; ssr[r] = 1;
        }
    }
    WAIT_LGKM();

    // ---- P2: mean column sums, quarter-row (rsub owns rows rsub*25..+24) ----
    f32x4 macc = {0.f, 0.f, 0.f, 0.f};
    for (int i = 0; i < 25; ++i) {
        const int row = rsub * 25 + i;
        const int s0 = ssr[row] - 1;
        macc += *(const f32x4*)(loc_emb + (size_t)s0 * EMB + csub * 4);
    }
    #pragma unroll
    for (int sh = 8; sh < 64; sh <<= 1) {
        macc[0] += __shfl_xor(macc[0], sh);
        macc[1] += __shfl_xor(macc[1], sh);
        macc[2] += __shfl_xor(macc[2], sh);
        macc[3] += __shfl_xor(macc[3], sh);
    }
    if (rsub == 0) *(f32x4*)(mloc + csub * 4) = macc;
    WAIT_LGKM();

    // ---- P3: m1[c] = b2 + (mloc@w1[:, :32]^T + cnt@T1t)/200  (mm regs, cnt streamed) ----
    {
        f32x4 mm[8];
        #pragma unroll
        for (int j = 0; j < 8; ++j) mm[j] = ((const f32x4*)mloc)[j];
        #pragma unroll
        for (int k = 0; k < 3; ++k) {
            const int c = lane + k * 64;
            if (c < COND) {
                f32x4 d = {0.f, 0.f, 0.f, 0.f};
                const f32x4* w1r = (const f32x4*)(w1 + (size_t)c * COND);
                #pragma unroll
                for (int j = 0; j < 8; ++j) d += mm[j] * w1r[j];
                const f32x4* t1r = (const f32x4*)(T1t + c * 52);
                #pragma unroll
                for (int q = 0; q < 13; ++q)
                    d += ((const f32x4*)cntW)[q] * t1r[q];
                m1W[c] = b2[c] + (d[0] + d[1] + d[2] + d[3]) * 0.005f;
            }
        }
    }
    WAIT_LGKM();

    // ---- P4: GEMM in two passes of 5 n-tiles (bf[5] live) ----
    #pragma unroll 1
    for (int g = 0; g < 2; ++g) {
        short8 bf[5]; float m1v[5], wcv[5];
        #pragma unroll
        for (int T5 = 0; T5 < 5; ++T5) {
            const int c = (g * 5 + T5) * 16 + lc;
            bf[T5]  = *(const short8*)(w2b + c * 32 + lg * 8);
            m1v[T5] = m1W[c];
            wcv[T5] = wc[c];
        }
        for (int m = 0; m < 13; ++m) {
            const int sA = ssr[m * 16 + lc] - 1;
            const uchar4 tq = *(const uchar4*)(ttr + m * 16 + lg * 4);
            const f32x4* ar = (const f32x4*)(loc_emb + (size_t)sA * EMB + lg * 8);
            const short8 av = pack8(ar[0], ar[1]);

            f32x4 acc[5];
            #pragma unroll
            for (int T5 = 0; T5 < 5; ++T5) {
                f32x4 z = {0.f, 0.f, 0.f, 0.f};
                acc[T5] = __builtin_amdgcn_mfma_f32_16x16x32_bf16(av, bf[T5], z, 0, 0, 0);
            }
            f32x4 srow;
            #pragma unroll
            for (int r = 0; r < 4; ++r) {
                const int t = (r == 0) ? tq.x : (r == 1) ? tq.y : (r == 2) ? tq.z : tq.w;
                const unsigned short* t2p = T2w2 + t * 256 + g * 128 + lc * 8;
                const ushort4 qa = *(const ushort4*)(t2p);
                const unsigned short q4 = t2p[4];
                float s = 0.0f;
                #pragma unroll
                for (int T5 = 0; T5 < 5; ++T5) {
                    const unsigned short t2u =
                        (T5 == 0) ? qa.x : (T5 == 1) ? qa.y :
                        (T5 == 2) ? qa.z : (T5 == 3) ? qa.w : q4;
                    const float x = acc[T5][r] + m1v[T5] + bf2f(t2u);
                    s = fmaf(wcv[T5], __builtin_amdgcn_rcpf(1.0f + __expf(-x)), s);
                }
                srow[r] = red16(s);
            }
            if (lc == 0) {
                #pragma unroll
                for (int r = 0; r < 4; ++r) {
                    const int row = m * 16 + lg * 4 + r;
                    if (row < LSEQ) {
                        if (g == 0) scoreW[row] = srow[r];
                        else        scoreW[row] += srow[r];
                    }
                }
            }
        }
        WAIT_LGKM();
    }

    // ---- P5a: sb histogram ----
    #pragma unroll
    for (int k = 0; k < 4; ++k) {
        const int r = lane + k * 64;
        if (r < LSEQ) {
            const int tt = ttr[r];
            if (tt != MASK_T) atomicAdd(&sbW[tt], scoreW[r]);
        }
    }
    // ---- P5b: uemb_loc quarter-row partials (re-gather from L2/L3) ----
    f32x4 uacc = {0.f, 0.f, 0.f, 0.f};
    for (int i = 0; i < 25; ++i) {
        const int row = rsub * 25 + i;
        const int s0 = ssr[row] - 1;
        const float sc = scoreW[row];
        const f32x4 v = *(const f32x4*)(loc_emb + (size_t)s0 * EMB + csub * 4);
        uacc[0] = fmaf(sc, v[0], uacc[0]);
        uacc[1] = fmaf(sc, v[1], uacc[1]);
        uacc[2] = fmaf(sc, v[2], uacc[2]);
        uacc[3] = fmaf(sc, v[3], uacc[3]);
    }
    #pragma unroll
    for (int sh = 8; sh < 64; sh <<= 1) {
        uacc[0] += __shfl_xor(uacc[0], sh);
        uacc[1] += __shfl_xor(uacc[1], sh);
        uacc[2] += __shfl_xor(uacc[2], sh);
        uacc[3] += __shfl_xor(uacc[3], sh);
    }
    if (rsub == 0) *(f32x4*)(su + 160 + csub * 4) = uacc;
    WAIT_LGKM();

    // ---- P5c: uemb_te[j] = sum_t sb[t]*te_t[j][t] (sb streamed from LDS) ----
    #pragma unroll
    for (int k = 0; k < 2; ++k) {
        const int j = lane + k * 64;     // 0..127
        const unsigned short* ter = te_t + j * 52;
        float s = 0.0f;
        #pragma unroll
        for (int q = 0; q < 13; ++q) {
            const f32x4 sq = ((const f32x4*)sbW)[q];
            const ushort4 tv = *(const ushort4*)(ter + q * 4);
            s = fmaf(sq[0], bf2f(tv.x), s);
            s = fmaf(sq[1], bf2f(tv.y), s);
            s = fmaf(sq[2], bf2f(tv.z), s);
            s = fmaf(sq[3], bf2f(tv.w), s);
        }
        su[192 + j] = s;
    }
    WAIT_LGKM();

    // ---- P6: broadcast-write rows 0..319 (1 KB contiguous per iteration) ----
    #pragma unroll 4
    for (int k = 0; k < 40; ++k) {
        const int idx = lane + k * 64;
        const int row = idx >> 3;
        const float v = su[row];
        f32x4 vv = {v, v, v, v};
        *(f32x4*)(outb + row * EMB + (idx & 7) * 4) = vv;
    }
}

extern "C" void kernel_launch(void* const* d_in, const int* in_sizes, int n_in,
                              void* d_out, int out_size, void* d_ws, size_t ws_size,
                              hipStream_t stream) {
    const int*   tp        = (const int*)  d_in[0];
    const int*   loc       = (const int*)  d_in[1];
    const float* emb       = (const float*)d_in[2];
    const int*   st        = (const int*)  d_in[3];
    const float* loc_emb   = (const float*)d_in[4];
    const float* noise     = (const float*)d_in[5];
    const int*   tstep     = (const int*)  d_in[6];
    const float* w1        = (const float*)d_in[7];
    const float* w2        = (const float*)d_in[8];
    const float* b2        = (const float*)d_in[9];
    const float* wc        = (const float*)d_in[10];
    const float* alpha_hat = (const float*)d_in[11];
    float* out = (float*)d_out;

    char* ws = (char*)d_ws;
    float*          T1t    = (float*)ws;                          // 33,280 B
    unsigned short* te_tab = (unsigned short*)(ws + 33280);       // 12,544 B
    unsigned short* te_t   = (unsigned short*)(ws + 45824);       // 13,312 B
    unsigned short* T2w2   = (unsigned short*)(ws + 59136);       // 25,088 B
    unsigned short* w2b    = (unsigned short*)(ws + 84224);       // 10,240 B

    prep<<<49, 256, 0, stream>>>(w1, w2, te_tab, T1t, te_t, T2w2, w2b);

    const int nb = in_sizes[0];   // 2048
    fusedw<<<nb, 64, 0, stream>>>(tp, loc, emb, st, loc_emb, noise, tstep,
                                  w1, w2b, te_tab, T1t, te_t, T2w2,
                                  b2, wc, alpha_hat, out);
}

// Round 16
// 75.945 us; speedup vs baseline: 1.5374x; 1.1295x over previous
//
#include <hip/hip_runtime.h>
#include <hip/hip_bf16.h>

#define LSEQ   200
#define LPAD   208
#define EMB    32
#define TDIM   128
#define COND   160
#define ROWS   321
#define MASK_T 48

typedef __attribute__((ext_vector_type(8))) short  short8;
typedef __attribute__((ext_vector_type(4))) float  f32x4;

__device__ __forceinline__ float bf2f(unsigned short u) {
    union { unsigned int i; float f; } v; v.i = ((unsigned int)u) << 16; return v.f;
}
__device__ __forceinline__ unsigned int f2bf(float f) {
    union { float f; unsigned int i; } v; v.f = f;
    unsigned int x = v.i;
    return ((x + 0x7fffu + ((x >> 16) & 1u)) >> 16);   // RNE, low 16
}
__device__ __forceinline__ unsigned int pack2(float lo, float hi) {
    return f2bf(lo) | (f2bf(hi) << 16);
}
__device__ __forceinline__ short8 pack8(f32x4 a, f32x4 b) {
    union { short8 s; unsigned int u[4]; } r;
    r.u[0] = pack2(a[0], a[1]); r.u[1] = pack2(a[2], a[3]);
    r.u[2] = pack2(b[0], b[1]); r.u[3] = pack2(b[2], b[3]);
    return r.s;
}

template<int CTRL>
__device__ __forceinline__ float dpp_add(float v) {
    const int x = __builtin_amdgcn_update_dpp(0, __float_as_int(v), CTRL, 0xf, 0xf, true);
    return v + __int_as_float(x);
}
__device__ __forceinline__ float red16(float v) {
    v = dpp_add<0x128>(v);   // row_ror:8
    v = dpp_add<0x124>(v);   // row_ror:4
    v = dpp_add<0x122>(v);   // row_ror:2
    v = dpp_add<0x121>(v);   // row_ror:1
    return v;
}

// ---- prep (49 blocks): te_tab[49][128] bf16; T1t[160][52] f32; te_t[128][52] bf16;
//      T2w2[49][2][16][8] bf16: tile T(0..9) -> wave g=T/5, slot=T%5:
//      T2w2[t][g][lc][slot] = T2[t][T*16+lc]; row t==48 -> 0.
//      Block 0 additionally emits w2b[160][32] bf16 (w2 cols 0..31, frag-ready).
__global__ void prep(const float* __restrict__ w1, const float* __restrict__ w2,
                     unsigned short* __restrict__ te_tab, float* __restrict__ T1t,
                     unsigned short* __restrict__ te_t, unsigned short* __restrict__ T2w2,
                     unsigned short* __restrict__ w2b) {
    __shared__ float te128[TDIM];
    const int t = blockIdx.x, tid = threadIdx.x;
    if (tid < 64) {
        const float dv = __expf(-0.14391156f * (float)tid);  // 10000^(-tid/64)
        const float a  = (float)t * dv;
        const float s  = __sinf(a), c = __cosf(a);
        te128[2 * tid] = s; te128[2 * tid + 1] = c;
        ((unsigned int*)te_tab)[t * 64 + tid] = pack2(s, c);
    }
    __syncthreads();
    if (tid < COND) {
        float s1 = 0.0f, s2 = 0.0f;
        const float* w1r = w1 + tid * COND + EMB;
        const float* w2r = w2 + tid * COND + EMB;
        #pragma unroll 8
        for (int j = 0; j < TDIM; ++j) {
            s1 = fmaf(te128[j], w1r[j], s1);
            s2 = fmaf(te128[j], w2r[j], s2);
        }
        if (t == MASK_T) { s1 = 0.0f; s2 = 0.0f; }
        T1t[tid * 52 + t] = s1;
        const int tile = tid >> 4, lcc = tid & 15;
        const int g = (tile >= 5) ? 1 : 0, slot = tile - 5 * g;
        T2w2[t * 256 + g * 128 + lcc * 8 + slot] = (unsigned short)f2bf(s2);
    }
    if (tid < TDIM) te_t[tid * 52 + t] = (unsigned short)f2bf(te128[tid]);
    if (t == 0 && tid < COND) {       // w2b row tid: cols 0..31 -> bf16
        const float* src = w2 + (size_t)tid * COND;
        unsigned int* dst = (unsigned int*)(w2b + tid * 32);
        #pragma unroll
        for (int j = 0; j < 16; ++j)
            dst[j] = pack2(src[2 * j], src[2 * j + 1]);
    }
}

// ---- main: one batch per 128-thread block (2 waves); wave g owns 5 n-tiles;
//      no LL staging (gather from L2/L3); LDS ~4.5 KB -> 16 blocks/CU possible ----
__global__ __launch_bounds__(128) __attribute__((amdgpu_waves_per_eu(4, 8)))
void fused2s(const int*   __restrict__ tp,
             const int*   __restrict__ loc,
             const float* __restrict__ emb,
             const int*   __restrict__ st,        // [B][L][2]
             const float* __restrict__ loc_emb,   // [V][32] fp32
             const float* __restrict__ noise,
             const int*   __restrict__ tstep,
             const float* __restrict__ w1,        // fp32 (cols 0..31 used)
             const unsigned short* __restrict__ w2b,    // [160][32] bf16
             const unsigned short* __restrict__ te_tab,
             const float* __restrict__ T1t,       // [160][52]
             const unsigned short* __restrict__ te_t,   // [128][52]
             const unsigned short* __restrict__ T2w2,   // [49][2][16][8]
             const float* __restrict__ b2,
             const float* __restrict__ wc,
             const float* __restrict__ alpha_hat,
             float* __restrict__ out)             // [B][321][32]
{
    __shared__ int   ssr[LPAD];                              // 832
    __shared__ float scoreW[LSEQ];                           // 800
    __shared__ float su[320];                                // 1,280 [side|uemb]
    __shared__ float m1W[COND];                              // 640
    __shared__ __attribute__((aligned(16))) float mupart[2][EMB]; // 256
    __shared__ __attribute__((aligned(16))) float cntW[52];  // 208
    __shared__ __attribute__((aligned(16))) float sbW[52];   // 208
    __shared__ __attribute__((aligned(4))) unsigned char ttr[LPAD]; // 208

    const int tid  = threadIdx.x;
    const int w    = tid >> 6, lane = tid & 63;
    const int b    = blockIdx.x;
    const int lc   = lane & 15, lg = lane >> 4;
    const int rsub = lane >> 3, csub = lane & 7;
    const int2* st2 = (const int2*)st;
    float* outb = out + (size_t)b * (ROWS * EMB);

    // ---- P0: side row + noisy row (w0); zero bins + scoreW (w1) ----
    if (w == 0) {
        if (lane < 32) {
            const ushort4 tv = *(const ushort4*)(te_tab + tp[b] * TDIM + lane * 4);
            f32x4 s4 = { bf2f(tv.x), bf2f(tv.y), bf2f(tv.z), bf2f(tv.w) };
            *(f32x4*)(su + lane * 4) = s4;
        } else if (lane < 40) {
            *(f32x4*)(su + 128 + (lane - 32) * 4) =
                *(const f32x4*)(loc_emb + (size_t)(loc[b] - 1) * EMB + (lane - 32) * 4);
        } else if (lane < 48) {
            const int e4 = lane - 40;
            const float a  = alpha_hat[tstep[b]];
            const float sa = sqrtf(a), sn = sqrtf(1.0f - a);
            const f32x4 ev = *(const f32x4*)(emb + (size_t)b * EMB + e4 * 4);
            const f32x4 nv = *(const f32x4*)(noise + (size_t)b * EMB + e4 * 4);
            f32x4 r = { sa*ev[0]+sn*nv[0], sa*ev[1]+sn*nv[1],
                        sa*ev[2]+sn*nv[2], sa*ev[3]+sn*nv[3] };
            *(f32x4*)(outb + 320 * EMB + e4 * 4) = r;
        }
    } else {
        if (lane < 52) { cntW[lane] = 0.0f; sbW[lane] = 0.0f; }
        if (lane < 50) {
            f32x4 z = {0.f, 0.f, 0.f, 0.f};
            *(f32x4*)(scoreW + lane * 4) = z;
        }
        if (lane >= 52 && lane < 60) { ttr[200 + lane - 52] = 0; ssr[200 + lane - 52] = 1; }
    }
    __syncthreads();   // B0

    // ---- P1: ttr/ssr + cnt histogram (wave w owns rows w*100..+99) ----
    #pragma unroll
    for (int k = 0; k < 2; ++k) {
        const int r = w * 100 + lane + k * 64;
        if (lane + k * 64 < 100) {
            const int2 sv = st2[(size_t)b * LSEQ + r];
            ttr[r] = (unsigned char)sv.y;
            ssr[r] = sv.x;
            if (sv.y != MASK_T) atomicAdd(&cntW[sv.y], 1.0f);
        }
    }

    // ---- P2: mean column sums, quarter-row over this wave's 100 rows ----
    f32x4 macc = {0.f, 0.f, 0.f, 0.f};
    #pragma unroll
    for (int i = 0; i < 13; ++i) {
        const int rr = i * 8 + rsub;
        if (rr < 100) {
            const int row = w * 100 + rr;
            const int s0 = st2[(size_t)b * LSEQ + row].x - 1;
            macc += *(const f32x4*)(loc_emb + (size_t)s0 * EMB + csub * 4);
        }
    }
    #pragma unroll
    for (int sh = 8; sh < 64; sh <<= 1) {
        macc[0] += __shfl_xor(macc[0], sh);
        macc[1] += __shfl_xor(macc[1], sh);
        macc[2] += __shfl_xor(macc[2], sh);
        macc[3] += __shfl_xor(macc[3], sh);
    }
    if (rsub == 0) *(f32x4*)(&mupart[w][csub * 4]) = macc;
    __syncthreads();   // B1

    // ---- P3: m1[c] = b2 + (colsum@w1[:, :32]^T + cnt@T1t)/200 ----
    #pragma unroll
    for (int k = 0; k < 2; ++k) {
        const int c = tid + k * 128;
        if (c < COND) {
            f32x4 d = {0.f, 0.f, 0.f, 0.f};
            const f32x4* w1r = (const f32x4*)(w1 + (size_t)c * COND);
            #pragma unroll
            for (int j = 0; j < 8; ++j) {
                const f32x4 mm = ((const f32x4*)mupart[0])[j] + ((const f32x4*)mupart[1])[j];
                d += mm * w1r[j];
            }
            const f32x4* t1r = (const f32x4*)(T1t + c * 52);
            #pragma unroll
            for (int q = 0; q < 13; ++q)
                d += ((const f32x4*)cntW)[q] * t1r[q];
            m1W[c] = b2[c] + (d[0] + d[1] + d[2] + d[3]) * 0.005f;
        }
    }
    __syncthreads();   // B2

    // ---- P4: GEMM: wave g=w owns n-tiles g*5..g*5+4; score via LDS atomics ----
    {
        const int g = w;
        short8 bf[5]; float m1v[5], wcv[5];
        #pragma unroll
        for (int T5 = 0; T5 < 5; ++T5) {
            const int c = (g * 5 + T5) * 16 + lc;
            bf[T5]  = *(const short8*)(w2b + c * 32 + lg * 8);
            m1v[T5] = m1W[c];
            wcv[T5] = wc[c];
        }
        for (int m = 0; m < 13; ++m) {
            const int sA = ssr[m * 16 + lc] - 1;
            const uchar4 tq = *(const uchar4*)(ttr + m * 16 + lg * 4);
            const f32x4* ar = (const f32x4*)(loc_emb + (size_t)sA * EMB + lg * 8);
            const short8 av = pack8(ar[0], ar[1]);

            f32x4 acc[5];
            #pragma unroll
            for (int T5 = 0; T5 < 5; ++T5) {
                f32x4 z = {0.f, 0.f, 0.f, 0.f};
                acc[T5] = __builtin_amdgcn_mfma_f32_16x16x32_bf16(av, bf[T5], z, 0, 0, 0);
            }
            f32x4 srow;
            #pragma unroll
            for (int r = 0; r < 4; ++r) {
                const int t = (r == 0) ? tq.x : (r == 1) ? tq.y : (r == 2) ? tq.z : tq.w;
                const unsigned short* t2p = T2w2 + t * 256 + g * 128 + lc * 8;
                const ushort4 qa = *(const ushort4*)(t2p);
                const unsigned short q4 = t2p[4];
                float s = 0.0f;
                #pragma unroll
                for (int T5 = 0; T5 < 5; ++T5) {
                    const unsigned short t2u =
                        (T5 == 0) ? qa.x : (T5 == 1) ? qa.y :
                        (T5 == 2) ? qa.z : (T5 == 3) ? qa.w : q4;
                    const float x = acc[T5][r] + m1v[T5] + bf2f(t2u);
                    s = fmaf(wcv[T5], __builtin_amdgcn_rcpf(1.0f + __expf(-x)), s);
                }
                srow[r] = red16(s);
            }
            if (lc == 0) {
                #pragma unroll
                for (int r = 0; r < 4; ++r) {
                    const int row = m * 16 + lg * 4 + r;
                    if (row < LSEQ) atomicAdd(&scoreW[row], srow[r]);
                }
            }
        }
    }
    __syncthreads();   // B3

    // ---- P5a: sb histogram (own rows) ----
    #pragma unroll
    for (int k = 0; k < 2; ++k) {
        const int rr = lane + k * 64;
        if (rr < 100) {
            const int r = w * 100 + rr;
            const int tt = ttr[r];
            if (tt != MASK_T) atomicAdd(&sbW[tt], scoreW[r]);
        }
    }
    // ---- P5b: uemb_loc quarter-row partials (re-gather from cache) ----
    f32x4 uacc = {0.f, 0.f, 0.f, 0.f};
    #pragma unroll
    for (int i = 0; i < 13; ++i) {
        const int rr = i * 8 + rsub;
        if (rr < 100) {
            const int row = w * 100 + rr;
            const int s0 = ssr[row] - 1;
            const float sc = scoreW[row];
            const f32x4 v = *(const f32x4*)(loc_emb + (size_t)s0 * EMB + csub * 4);
            uacc[0] = fmaf(sc, v[0], uacc[0]);
            uacc[1] = fmaf(sc, v[1], uacc[1]);
            uacc[2] = fmaf(sc, v[2], uacc[2]);
            uacc[3] = fmaf(sc, v[3], uacc[3]);
        }
    }
    #pragma unroll
    for (int sh = 8; sh < 64; sh <<= 1) {
        uacc[0] += __shfl_xor(uacc[0], sh);
        uacc[1] += __shfl_xor(uacc[1], sh);
        uacc[2] += __shfl_xor(uacc[2], sh);
        uacc[3] += __shfl_xor(uacc[3], sh);
    }
    if (rsub == 0) *(f32x4*)(&mupart[w][csub * 4]) = uacc;
    __syncthreads();   // B4

    // ---- P5c: uemb_te (all 128 threads) + uemb_loc combine (tid<32) ----
    {
        const int j = tid;                               // 0..127
        const unsigned short* ter = te_t + j * 52;
        float s = 0.0f;
        #pragma unroll
        for (int q = 0; q < 13; ++q) {
            const f32x4 sq = ((const f32x4*)sbW)[q];
            const ushort4 tv = *(const ushort4*)(ter + q * 4);
            s = fmaf(sq[0], bf2f(tv.x), s);
            s = fmaf(sq[1], bf2f(tv.y), s);
            s = fmaf(sq[2], bf2f(tv.z), s);
            s = fmaf(sq[3], bf2f(tv.w), s);
        }
        su[192 + j] = s;
    }
    if (tid < 32) su[160 + tid] = mupart[0][tid] + mupart[1][tid];
    __syncthreads();   // B5

    // ---- P6: broadcast-write rows 0..319 ----
    #pragma unroll
    for (int k = 0; k < 20; ++k) {
        const int idx = tid + k * 128;
        const int row = idx >> 3;
        const float v = su[row];
        f32x4 vv = {v, v, v, v};
        *(f32x4*)(outb + row * EMB + (idx & 7) * 4) = vv;
    }
}

extern "C" void kernel_launch(void* const* d_in, const int* in_sizes, int n_in,
                              void* d_out, int out_size, void* d_ws, size_t ws_size,
                              hipStream_t stream) {
    const int*   tp        = (const int*)  d_in[0];
    const int*   loc       = (const int*)  d_in[1];
    const float* emb       = (const float*)d_in[2];
    const int*   st        = (const int*)  d_in[3];
    const float* loc_emb   = (const float*)d_in[4];
    const float* noise     = (const float*)d_in[5];
    const int*   tstep     = (const int*)  d_in[6];
    const float* w1        = (const float*)d_in[7];
    const float* w2        = (const float*)d_in[8];
    const float* b2        = (const float*)d_in[9];
    const float* wc        = (const float*)d_in[10];
    const float* alpha_hat = (const float*)d_in[11];
    float* out = (float*)d_out;

    char* ws = (char*)d_ws;
    float*          T1t    = (float*)ws;                          // 33,280 B
    unsigned short* te_tab = (unsigned short*)(ws + 33280);       // 12,544 B
    unsigned short* te_t   = (unsigned short*)(ws + 45824);       // 13,312 B
    unsigned short* T2w2   = (unsigned short*)(ws + 59136);       // 25,088 B
    unsigned short* w2b    = (unsigned short*)(ws + 84224);       // 10,240 B

    prep<<<49, 256, 0, stream>>>(w1, w2, te_tab, T1t, te_t, T2w2, w2b);

    const int nb = in_sizes[0];   // 2048
    fused2s<<<nb, 128, 0, stream>>>(tp, loc, emb, st, loc_emb, noise, tstep,
                                    w1, w2b, te_tab, T1t, te_t, T2w2,
                                    b2, wc, alpha_hat, out);
}